// Round 1
// baseline (105.576 us; speedup 1.0000x reference)
//
#include <hip/hip_runtime.h>
#include <hip/hip_bf16.h>

// ---------------------------------------------------------------------------
// Adalibi: out[n,0,h,p*N+c] = (inv_p[n]==c) * sqrt(exp(slope_h)) / sqrt(P)
//   N=2048, H=16, P=2, k=37. Output f32, 2048*16*4096 = 134,217,728 elems.
// inv_p[n] = #{m in 1..n : ceil((t_m-u_p)/d_p) != ceil((t_{m-1}-u_p)/d_p)}
// ---------------------------------------------------------------------------

#define N_SEQ 2048
#define H_NUM 16
#define P_NUM 2

// Kernel A: per-p binning + inclusive scan of change flags -> inv[p][n]
__global__ void binning_kernel(const float* __restrict__ delta,
                               const float* __restrict__ u,
                               const int* __restrict__ kptr,
                               int* __restrict__ inv) {
    const int p = blockIdx.x;           // 0..P_NUM-1
    const int t = threadIdx.x;          // 0..1023
    const float dp = delta[p];
    const float up = u[p];
    const int kk = kptr[0];

    __shared__ int s[2][N_SEQ];

    // change flags, mirroring reference f32 arithmetic exactly:
    // idx = (int)ceilf(((float)(kk+n) - up) / dp)
    for (int j = t; j < N_SEQ; j += 1024) {
        int idx = (int)ceilf(((float)(kk + j) - up) / dp);
        int flag = 0;
        if (j > 0) {
            int idxm = (int)ceilf(((float)(kk + j - 1) - up) / dp);
            flag = (idx != idxm) ? 1 : 0;
        }
        s[0][j] = flag;
    }
    __syncthreads();

    // Hillis-Steele inclusive scan over 2048 entries (11 steps, ping-pong)
    int src = 0;
    for (int off = 1; off < N_SEQ; off <<= 1) {
        int dst = src ^ 1;
        for (int j = t; j < N_SEQ; j += 1024) {
            int v = s[src][j];
            if (j >= off) v += s[src][j - off];
            s[dst][j] = v;
        }
        __syncthreads();
        src = dst;
    }

    for (int j = t; j < N_SEQ; j += 1024)
        inv[p * N_SEQ + j] = s[src][j];
}

// Kernel B: write the full 536.9 MB output; one float4 store per iteration.
// stride (gridDim*blockDim) must be a multiple of 16384 float4s so that
// h, col0, p are per-thread loop invariants (row advances by a multiple of 16).
__global__ __launch_bounds__(256) void fill_kernel(const int* __restrict__ inv,
                                                   float4* __restrict__ out) {
    __shared__ float sval[H_NUM];
    if (threadIdx.x < H_NUM) {
        int h = threadIdx.x;
        // slope_h = 2^(-(h+1)/2);  val = sqrt(exp(slope)) * (1/sqrt(2))
        float slope = exp2f(-0.5f * (float)(h + 1));
        sval[h] = sqrtf(expf(slope)) * 0.70710678118f;
    }
    __syncthreads();

    const size_t TOTAL = (size_t)N_SEQ * H_NUM * (P_NUM * N_SEQ) / 4; // 33,554,432
    const size_t g = (size_t)blockIdx.x * blockDim.x + threadIdx.x;
    const size_t stride = (size_t)gridDim.x * blockDim.x; // 524288 (mult of 16384)

    // loop-invariant decomposition of the flat float4 index:
    //   row  = i >> 10  (4096 floats = 1024 float4 per row)
    //   h    = row & 15, n = row >> 4
    //   col0 = (i & 1023) * 4 ;  p = col0 >> 11 ; c = col0 & 2047
    const int h = (int)((g >> 10) & 15);
    const int col0 = (int)(g & 1023) << 2;
    const int p = col0 >> 11;
    const int c = col0 & 2047;
    const float v = sval[h];
    const int* __restrict__ invp = inv + p * N_SEQ;

    for (size_t i = g; i < TOTAL; i += stride) {
        const int n = (int)(i >> 14);     // (i>>10)>>4
        const int tgt = invp[n];
        float4 o;
        o.x = (tgt == c)     ? v : 0.0f;
        o.y = (tgt == c + 1) ? v : 0.0f;
        o.z = (tgt == c + 2) ? v : 0.0f;
        o.w = (tgt == c + 3) ? v : 0.0f;
        out[i] = o;
    }
}

extern "C" void kernel_launch(void* const* d_in, const int* in_sizes, int n_in,
                              void* d_out, int out_size, void* d_ws, size_t ws_size,
                              hipStream_t stream) {
    // inputs: [0]=x (unused, dtype only), [1]=delta (P,1) f32, [2]=u (P,1) f32,
    //         [3]=seq_len (int), [4]=k (int)
    const float* delta = (const float*)d_in[1];
    const float* u     = (const float*)d_in[2];
    const int*   kptr  = (const int*)d_in[4];
    int* inv = (int*)d_ws;                    // int inv[P_NUM][N_SEQ] = 16 KB

    binning_kernel<<<P_NUM, 1024, 0, stream>>>(delta, u, kptr, inv);
    fill_kernel<<<2048, 256, 0, stream>>>(inv, (float4*)d_out);
}